// Round 1
// 215.960 us; speedup vs baseline: 1.0039x; 1.0039x over previous
//
#include <hip/hip_runtime.h>

// J-loss via MFMA: T[b,i,k] = sum_p pred[b,i,p] * onehot(target[b,p]==k)
// j[b] = -sum_{i!=k} log(0.5 + 0.5*(T[b,i,i]/n[b,i] - T[b,i,k]/n[b,k]))
//
// R8 (best, 216.8us): R3 structure + nontemporal loads.
// R9 analysis: top-5 rocprof dispatches are all 88us/576MiB harness poison
// fills -> jloss_mfma < 88us; consistent decomposition = ~176us fixed fills
// + ~37us mfma kernel vs ~26us HBM roofline. Gap = tail quantization
// (1152 blocks = 4.5/CU -> 11% makespan loss) + borderline latency hiding
// (12 loads in flight, 4 waves/SIMD * 220cy ~= 900cy HBM latency).
// R9 = two co-targeted changes, everything else byte-identical:
//   (1) CHUNK_PX 1024->1152: grid = 8*128 = 1024 = exactly 4 blocks/CU.
//   (2) 9 K-steps, unroll 2->3: 18 loads in flight (1320cy compute cover).

#define BB 8
#define CC 32
#define HW 147456                 // 384*384 = 128 * 1152
#define CHUNK_PX 1152             // pixels per block (4 waves x 288 px)
#define NCHUNK (HW / CHUNK_PX)    // 128 -> grid 1024 = 4 blocks/CU exact
#define KSTEPS (CHUNK_PX / 4 / 32) // 9 K-steps of 32 px per wave

typedef __attribute__((ext_vector_type(8))) short short8;
typedef __attribute__((ext_vector_type(4))) float float4v;
typedef __attribute__((ext_vector_type(4))) unsigned uint4v;
typedef __attribute__((ext_vector_type(4))) int int4v;

// pack trunc-bf16(lo), trunc-bf16(hi) into one dword: 1 v_perm_b32
__device__ __forceinline__ unsigned pk(float lo, float hi) {
    return __builtin_amdgcn_perm(__float_as_uint(hi), __float_as_uint(lo), 0x07060302u);
}
// packed pair of one-hot bf16 values for classes (ta,tb) vs m
__device__ __forceinline__ unsigned oh2(int ta, int tb, int m) {
    return (ta == m ? 0x3F80u : 0u) | (tb == m ? 0x3F800000u : 0u);
}

__global__ __launch_bounds__(256, 4) void jloss_mfma(
    const float* __restrict__ pred,    // [B][C][HW]
    const int*   __restrict__ target,  // [B][HW]
    float*       __restrict__ T,       // [B][C][C] pre-zeroed
    float*       __restrict__ cnt)     // [B][C]    pre-zeroed
{
    const int tid  = threadIdx.x;
    const int w    = tid >> 6;         // wave 0..3
    const int l    = tid & 63;
    const int quad = l >> 4;
    const int m    = l & 15;
    const int blk  = blockIdx.x;
    const int b    = blk / NCHUNK;     // NCHUNK=128 -> shift
    const int chunk= blk % NCHUNK;

    const long pb_wave = (long)chunk * CHUNK_PX + w * (CHUNK_PX / 4);
    const float* predb = pred + (long)b * CC * HW;
    const int*   tgtb  = target + (long)b * HW;

    float4v acc00 = {0,0,0,0}, acc01 = {0,0,0,0};
    float4v acc10 = {0,0,0,0}, acc11 = {0,0,0,0};
    float4v accc0 = {0,0,0,0}, accc1 = {0,0,0,0};   // counts: ones . B
    const short8 ONES = {0x3F80,0x3F80,0x3F80,0x3F80,0x3F80,0x3F80,0x3F80,0x3F80};

    #pragma unroll 3
    for (int ks = 0; ks < KSTEPS; ++ks) {   // 9 K-steps of 32 pixels
        const long po = pb_wave + ks * 32 + quad * 8;
        const float* p0 = predb + (long)m * HW + po;   // channel m
        const float* p1 = p0 + (long)16 * HW;          // channel m+16
        const float4v a0l = __builtin_nontemporal_load((const float4v*)p0);
        const float4v a0h = __builtin_nontemporal_load((const float4v*)(p0 + 4));
        const float4v a1l = __builtin_nontemporal_load((const float4v*)p1);
        const float4v a1h = __builtin_nontemporal_load((const float4v*)(p1 + 4));
        const int4v t0 = __builtin_nontemporal_load((const int4v*)(tgtb + po));
        const int4v t1 = __builtin_nontemporal_load((const int4v*)(tgtb + po + 4));

        union { short8 s; uint4v u; } A0, A1, B0, B1;
        A0.u[0] = pk(a0l[0], a0l[1]); A0.u[1] = pk(a0l[2], a0l[3]);
        A0.u[2] = pk(a0h[0], a0h[1]); A0.u[3] = pk(a0h[2], a0h[3]);
        A1.u[0] = pk(a1l[0], a1l[1]); A1.u[1] = pk(a1l[2], a1l[3]);
        A1.u[2] = pk(a1h[0], a1h[1]); A1.u[3] = pk(a1h[2], a1h[3]);
        B0.u[0] = oh2(t0[0], t0[1], m);      B0.u[1] = oh2(t0[2], t0[3], m);
        B0.u[2] = oh2(t1[0], t1[1], m);      B0.u[3] = oh2(t1[2], t1[3], m);
        const int m16 = m + 16;
        B1.u[0] = oh2(t0[0], t0[1], m16);    B1.u[1] = oh2(t0[2], t0[3], m16);
        B1.u[2] = oh2(t1[0], t1[1], m16);    B1.u[3] = oh2(t1[2], t1[3], m16);

        acc00 = __builtin_amdgcn_mfma_f32_16x16x32_bf16(A0.s, B0.s, acc00, 0, 0, 0);
        acc01 = __builtin_amdgcn_mfma_f32_16x16x32_bf16(A0.s, B1.s, acc01, 0, 0, 0);
        acc10 = __builtin_amdgcn_mfma_f32_16x16x32_bf16(A1.s, B0.s, acc10, 0, 0, 0);
        acc11 = __builtin_amdgcn_mfma_f32_16x16x32_bf16(A1.s, B1.s, acc11, 0, 0, 0);
        accc0 = __builtin_amdgcn_mfma_f32_16x16x32_bf16(ONES, B0.s, accc0, 0, 0, 0);
        accc1 = __builtin_amdgcn_mfma_f32_16x16x32_bf16(ONES, B1.s, accc1, 0, 0, 0);
    }

    // cross-wave reduce in LDS, then one global atomic per entry
    __shared__ float red[4][CC][CC];   // 16 KB
    __shared__ float redc[4][CC];
    #pragma unroll
    for (int r = 0; r < 4; ++r) {      // C layout: row=quad*4+r, col=m (m89-verified)
        red[w][quad*4 + r     ][m     ] = acc00[r];
        red[w][quad*4 + r     ][m + 16] = acc01[r];
        red[w][quad*4 + r + 16][m     ] = acc10[r];
        red[w][quad*4 + r + 16][m + 16] = acc11[r];
    }
    if (quad == 0) {                   // counts: every row of accc is count[col]
        redc[w][m]      = accc0[0];
        redc[w][m + 16] = accc1[0];
    }
    __syncthreads();

    float* Tb = T + (long)b * CC * CC;
    const float* rp = &red[0][0][0];
    for (int j = tid; j < CC * CC; j += 256) {
        const float s = rp[j] + rp[1024 + j] + rp[2048 + j] + rp[3072 + j];
        atomicAdd(&Tb[j], s);
    }
    if (tid < CC)
        atomicAdd(&cnt[b * CC + tid],
                  redc[0][tid] + redc[1][tid] + redc[2][tid] + redc[3][tid]);
}

__global__ __launch_bounds__(256) void jloss_final(
    const float* __restrict__ T,
    const float* __restrict__ cnt,
    float*       __restrict__ out)
{
    const int b   = blockIdx.x;
    const int tid = threadIdx.x;
    __shared__ float diag_s[CC];
    __shared__ float inv_n[CC];
    __shared__ float wsum[4];

    const float* Tb = T + (long)b * CC * CC;
    const float* cb = cnt + b * CC;

    if (tid < CC) {
        const float inv = 1.0f / cb[tid];
        inv_n[tid]  = inv;
        diag_s[tid] = Tb[tid * CC + tid] * inv;
    }
    __syncthreads();

    float sum = 0.0f;
    for (int idx = tid; idx < CC * CC; idx += 256) {
        const int i = idx >> 5;
        const int k = idx & 31;
        if (i != k) {
            const float S = Tb[idx] * inv_n[k];
            sum += logf(0.5f + 0.5f * (diag_s[i] - S));
        }
    }
    #pragma unroll
    for (int off = 32; off > 0; off >>= 1) sum += __shfl_down(sum, off, 64);
    if ((tid & 63) == 0) wsum[tid >> 6] = sum;
    __syncthreads();
    if (tid == 0) out[b] = -(wsum[0] + wsum[1] + wsum[2] + wsum[3]);
}

extern "C" void kernel_launch(void* const* d_in, const int* in_sizes, int n_in,
                              void* d_out, int out_size, void* d_ws, size_t ws_size,
                              hipStream_t stream) {
    const float* pred   = (const float*)d_in[0];
    const int*   target = (const int*)d_in[1];
    float* out = (float*)d_out;

    float* T   = (float*)d_ws;                       // 8*32*32 floats
    float* cnt = (float*)d_ws + BB * CC * CC;        // 8*32 floats

    hipMemsetAsync(d_ws, 0, (BB * CC * CC + BB * CC) * sizeof(float), stream);

    jloss_mfma <<<BB * NCHUNK, 256, 0, stream>>>(pred, target, T, cnt);
    jloss_final<<<BB, 256, 0, stream>>>(T, cnt, out);
}